// Round 16
// baseline (260.974 us; speedup 1.0000x reference)
//
#include <hip/hip_runtime.h>
#include <cstdint>

#define B_SZ   512
#define IN_SZ  3072
#define HID    2048
#define OUT_SZ 512
#define T_STEPS 10
#define NELEM  (512u*3072u)
#define KW     96                    // in_bits words per row
#define BITS_T_STRIDE (512u*96u)
#define M_ALL  (T_STEPS * B_SZ)      // 5120 rows in the de-fused hidden GEMM

typedef __attribute__((ext_vector_type(8))) short short8v;    // 8 bf16
typedef __attribute__((ext_vector_type(4))) float f32x4;
typedef __attribute__((ext_vector_type(16))) float f32x16;
typedef __attribute__((ext_vector_type(4))) unsigned int u32x4;

struct Keys { uint32_t k[2*T_STEPS]; };

__host__ __device__ inline void threefry2x32(uint32_t k0, uint32_t k1,
                                             uint32_t x0, uint32_t x1,
                                             uint32_t& y0, uint32_t& y1) {
  const uint32_t ks2 = k0 ^ k1 ^ 0x1BD11BDAu;
#define TF_R(r) { x0 += x1; x1 = (x1 << (r)) | (x1 >> (32-(r))); x1 ^= x0; }
  x0 += k0; x1 += k1;
  TF_R(13) TF_R(15) TF_R(26) TF_R(6)   x0 += k1;  x1 += ks2 + 1u;
  TF_R(17) TF_R(29) TF_R(16) TF_R(24)  x0 += ks2; x1 += k0  + 2u;
  TF_R(13) TF_R(15) TF_R(26) TF_R(6)   x0 += k0;  x1 += k1  + 3u;
  TF_R(17) TF_R(29) TF_R(16) TF_R(24)  x0 += k1;  x1 += ks2 + 4u;
  TF_R(13) TF_R(15) TF_R(26) TF_R(6)   x0 += ks2; x1 += k0  + 5u;
#undef TF_R
  y0 = x0; y1 = x1;
}

// ---------------- exact 3-way bf16 split helpers ---------------------------
__device__ __forceinline__ ushort rne_bf16(float f) {
  uint32_t u = __float_as_uint(f);
  return (ushort)((u + 0x7FFFu + ((u >> 16) & 1u)) >> 16);
}

__device__ __forceinline__ void split3x8(const float* __restrict__ src,
                                         short8v& hv, short8v& mv, short8v& lv) {
  float w8[8];
  *(f32x4*)&w8[0] = *(const f32x4*)&src[0];
  *(f32x4*)&w8[4] = *(const f32x4*)&src[4];
  union { ushort u[8]; short8v v; } h8, m8, l8;
#pragma unroll
  for (int j = 0; j < 8; ++j) {
    float w = w8[j];
    ushort h = rne_bf16(w);
    float hf = __uint_as_float((uint32_t)h << 16);
    float r1 = w - hf;                     // exact
    ushort m = rne_bf16(r1);
    float mf = __uint_as_float((uint32_t)m << 16);
    float r2 = r1 - mf;                    // exact
    ushort l = rne_bf16(r2);               // exact
    h8.u[j] = h; m8.u[j] = m; l8.u[j] = l;
  }
  hv = h8.v; mv = m8.v; lv = l8.v;
}

// ---------------- bit byte -> 8 bf16 {0,1} ---------------------------------
__device__ __forceinline__ short8v expand8(uint32_t b) {
  union { uint32_t u[4]; short8v v; } r;
#pragma unroll
  for (int j = 0; j < 4; ++j) {
    uint32_t x = b >> (2*j);
    r.u[j] = ((x & 1u) | ((x & 2u) << 15)) * 0x3F80u;  // bf16 1.0 per set bit
  }
  return r.v;
}

// ---------------- fused prep: split32(Win) + split16(Wout) + spikegen ------
// blocks [0,3072): split_frag32; [3072,3584): split_frag; [3584,9728): spikegen
__global__ __launch_bounds__(256) void prep_kernel(
    const float* __restrict__ x, const float* __restrict__ Win,
    const float* __restrict__ Wout,
    ushort* __restrict__ Wfrag, ushort* __restrict__ Ofrag,
    uint32_t* __restrict__ pre_bits, Keys keys) {
  int blk = blockIdx.x;
  int tid = threadIdx.x;
  if (blk < 3072) {
    // 32-col fragment layout (verified rounds 8-15):
    // out[nt32][ks16][3][512], entry (kh*32+c)*8+e = W[nt*32+c][ks*16+kh*8+e]
    int bx = blk % 48, nt = blk / 48;
    int col = tid & 31;
    int cell = tid >> 5;
    int ks = bx * 4 + (cell >> 1);
    int kh = cell & 1;
    short8v hv, mv, lv;
    split3x8(&Win[(size_t)(nt * 32 + col) * IN_SZ + ks * 16 + kh * 8],
             hv, mv, lv);
    size_t base =
        ((size_t)nt * (IN_SZ / 16) + ks) * (3 * 512) + (kh * 32 + col) * 8;
    *(short8v*)&Wfrag[base]        = hv;
    *(short8v*)&Wfrag[base + 512]  = mv;
    *(short8v*)&Wfrag[base + 1024] = lv;
  } else if (blk < 3584) {
    // 16-col fragment layout (verified rounds 5-15)
    int q = blk - 3072;
    int bx = q % 16, nt = q / 16;
    int ks = bx * 4 + (tid >> 6);
    int kb = (tid >> 4) & 3, c = tid & 15;
    short8v hv, mv, lv;
    split3x8(&Wout[(size_t)(nt * 16 + c) * HID + ks * 32 + kb * 8],
             hv, mv, lv);
    size_t base =
        ((size_t)nt * (HID / 32) + ks) * (3 * 512) + (kb * 16 + c) * 8;
    *(short8v*)&Ofrag[base]        = hv;
    *(short8v*)&Ofrag[base + 512]  = mv;
    *(short8v*)&Ofrag[base + 1024] = lv;
  } else {
    // spike generation (verified rounds 1/3-15)
    uint32_t m = (uint32_t)(blk - 3584) * 256u + tid;
    uint32_t b = m / IN_SZ;
    uint32_t j = m - b * IN_SZ;
    float xv = x[m];
    float p = (float)(1.0 / (1.0 + exp(-(double)xv)));
    uint32_t lane = tid & 63u;
    uint32_t wbase = b * KW + (j >> 5);
#pragma unroll
    for (int t = 0; t < T_STEPS; ++t) {
      uint32_t y0, y1;
      threefry2x32(keys.k[2*t], keys.k[2*t+1], 0u, m, y0, y1);
      uint32_t bits = y0 ^ y1;
      float u = __uint_as_float((bits >> 9) | 0x3f800000u) - 1.0f;
      unsigned long long mask = __ballot(u < p);
      if (lane == 0u) {
        *reinterpret_cast<unsigned long long*>(
            &pre_bits[(uint32_t)t * BITS_T_STRIDE + wbase]) = mask;
      }
    }
  }
}

#define MFMA(a, b, c)   __builtin_amdgcn_mfma_f32_16x16x32_bf16((a), (b), (c), 0, 0, 0)
#define MFMA32(a, b, c) __builtin_amdgcn_mfma_f32_32x32x16_bf16((a), (b), (c), 0, 0, 0)

// ---------------- hidden GEMM: R15 + burst-first chunk body ----------------
// 256 thr (4 waves 1m x 4n), tile 160m x 128n; wave = 160m x 32n (F=5).
// grid 512 = 8 XCD x 2 xb x 32 mb -> 2 blocks/CU; LDS 40 KB; panel-ordered.
// Chunk body: s=0 burst FIRST (MFMA pipe restarts right after barrier),
// then STAGE + bits prefetch under its shadow, then s=1..3 bursts.
// FP order per (m,n) identical to rounds 8-15.
__global__ __launch_bounds__(256) void gemm_hidden(
    const ushort* __restrict__ Wfrag,       // [64 nt][192 ks][3][512]
    const uint32_t* __restrict__ in_bits,   // [5120][96]
    float* __restrict__ H) {                // [5120][2048]
  __shared__ ushort A_lds[2][10240];        // [8 j][5 f][32 row][8 e] x2 = 40KB
  int lin = blockIdx.x;
  int xcd = lin & 7, w = lin >> 3;          // w 0..63
  int xb  = xcd * 2 + (w >> 5);             // n-panel: all mb of panel0 first
  int mb  = w & 31;                         // m-block (160 rows), 0..31
  int tid  = threadIdx.x;
  int wave = tid >> 6, lane = tid & 63;
  int col  = lane & 31, kh = lane >> 5;
  int nt = xb * 4 + wave;                   // 32-col group
  int m0 = mb * 160;
  const ushort* bp = Wfrag + (size_t)nt * (192 * 3 * 512);

  // staging: byte-slot s = r*8 + j (r row 0..159, j chunk-byte 0..7);
  // thread owns slots 5t..5t+4 -> spans rows r0..r1 (r1==r0 or r0+1);
  // per chunk: 2 b64 loads deliver both rows' two 32-bit words.
  int s0 = tid * 5;
  int r0 = s0 >> 3, r1 = (s0 + 4) >> 3;
  const uint32_t* rowp0 = in_bits + (size_t)(m0 + r0) * KW;
  const uint32_t* rowp1 = in_bits + (size_t)(m0 + r1) * KW;
  int hi_[5], ws_[5], sh_[5], off_[5];
#pragma unroll
  for (int p = 0; p < 5; ++p) {
    int s = s0 + p, r = s >> 3, j = s & 7;
    hi_[p]  = (r != r0);
    ws_[p]  = (j >> 2) & 1;
    sh_[p]  = (j & 3) * 8;
    off_[p] = (j * 5 + (r >> 5)) * 256 + (r & 31) * 8;
  }

  f32x16 acc[5];
#pragma unroll
  for (int f = 0; f < 5; ++f)
#pragma unroll
    for (int r = 0; r < 16; ++r) acc[f][r] = 0.f;

  uint2 br0, br1;   // bits words (2 per row) for the chunk being staged

#define STAGE(buf)                                                            \
  {                                                                           \
    _Pragma("unroll")                                                         \
    for (int p = 0; p < 5; ++p) {                                             \
      uint32_t wv = hi_[p] ? (ws_[p] ? br1.y : br1.x)                         \
                           : (ws_[p] ? br0.y : br0.x);                        \
      *(short8v*)&A_lds[buf][off_[p]] = expand8((wv >> sh_[p]) & 0xFFu);      \
    }                                                                         \
  }

#define BURST(sidx)                                                           \
  {                                                                           \
    int g2 = kc * 4 + (sidx) + 2;                                             \
    if (g2 > 191) g2 = 191;                                                   \
    const ushort* bn = bp + (size_t)g2 * 1536 + lane * 8;                     \
    short8v Bn0 = *(const short8v*)&bn[0];                                    \
    short8v Bn1 = *(const short8v*)&bn[512];                                  \
    short8v Bn2 = *(const short8v*)&bn[1024];                                 \
    short8v A[5];                                                             \
    _Pragma("unroll")                                                         \
    for (int f = 0; f < 5; ++f)                                               \
      A[f] = *(const short8v*)&A_lds[cur][(sidx) * 2560 + aoff + f * 256];    \
    __builtin_amdgcn_s_setprio(1);                                            \
    _Pragma("unroll")                                                         \
    for (int f = 0; f < 5; ++f) acc[f] = MFMA32(A[f], Bc0, acc[f]);           \
    _Pragma("unroll")                                                         \
    for (int f = 0; f < 5; ++f) acc[f] = MFMA32(A[f], Bc1, acc[f]);           \
    _Pragma("unroll")                                                         \
    for (int f = 0; f < 5; ++f) acc[f] = MFMA32(A[f], Bc2, acc[f]);           \
    __builtin_amdgcn_s_setprio(0);                                            \
    Bc0 = Bd0; Bc1 = Bd1; Bc2 = Bd2;                                          \
    Bd0 = Bn0; Bd1 = Bn1; Bd2 = Bn2;                                          \
  }

  // prologue: stage chunk 0, prefetch bits chunk 1, preload B[g=0], B[g=1]
  br0 = *(const uint2*)&rowp0[0];
  br1 = *(const uint2*)&rowp1[0];
  STAGE(0)
  br0 = *(const uint2*)&rowp0[2];
  br1 = *(const uint2*)&rowp1[2];
  short8v Bc0, Bc1, Bc2, Bd0, Bd1, Bd2;
  {
    const ushort* bk = bp + lane * 8;
    Bc0 = *(const short8v*)&bk[0];
    Bc1 = *(const short8v*)&bk[512];
    Bc2 = *(const short8v*)&bk[1024];
    const ushort* bd = bk + 1536;
    Bd0 = *(const short8v*)&bd[0];
    Bd1 = *(const short8v*)&bd[512];
    Bd2 = *(const short8v*)&bd[1024];
  }
  __syncthreads();

  int aoff = kh * 5 * 256 + col * 8;   // wave's A-frag base within a j-pair

  for (int kc = 0; kc < 48; ++kc) {
    int cur = kc & 1;
    BURST(0)                                         // restart pipe at once
    if (kc + 1 < 48) STAGE(cur ^ 1)                  // under s=0's shadow
    if (kc + 2 < 48) {                               // prefetch chunk kc+2
      br0 = *(const uint2*)&rowp0[(kc + 2) * 2];
      br1 = *(const uint2*)&rowp1[(kc + 2) * 2];
    }
    BURST(1)
    BURST(2)
    BURST(3)
    __syncthreads();
  }
#undef BURST
#undef STAGE

  // C layout (verified m74/m101, rounds 8-15): col=lane&31,
  // row=(r&3)+8*(r>>2)+4*kh
#pragma unroll
  for (int f = 0; f < 5; ++f)
#pragma unroll
    for (int r = 0; r < 16; ++r) {
      int m = m0 + f * 32 + (r & 3) + 8 * (r >> 2) + 4 * kh;
      H[(size_t)m * HID + nt * 32 + col] = acc[f][r];
    }
}

// ---------------- LIF scan over t (the only sequential part) ---------------
__global__ __launch_bounds__(256) void lif_scan(
    const float* __restrict__ H,           // [5120][2048]
    uint8_t* __restrict__ spk) {           // [T][512][256] bit-packed along n
  int idx  = blockIdx.x * 256 + threadIdx.x;   // 0 .. 512*2048-1
  int b = idx >> 11, n = idx & 2047;
  int lane = threadIdx.x & 63;
  size_t spk_off = (size_t)b * 256 + (size_t)((n >> 3) & ~7);
  float v = 0.f;
#pragma unroll
  for (int t = 0; t < T_STEPS; ++t) {
    float h = H[(size_t)(t * B_SZ + b) * HID + n];
    bool fire;
    {
#pragma clang fp contract(off)
      float vd = v * 0.3f;
      float vn = vd + h;
      fire = (vn >= 1.0f);
      v = fire ? 0.0f : vn;
    }
    unsigned long long mask = __ballot(fire);
    if (lane == 0)
      *(unsigned long long*)&spk[(size_t)t * (512*256) + spk_off] = mask;
  }
}

// ---------------- output layer: 1280 blocks (5/CU balanced), pipelined -----
__global__ __launch_bounds__(256) void out_mfma(
    const ushort* __restrict__ Ofrag,       // [32][64][3][512]
    const uint8_t* __restrict__ spk,        // [T][512][256]
    const float* __restrict__ bout,
    float* __restrict__ s) {                // [512][512], pre-zeroed
  int lin = blockIdx.x;
  int x = lin & 7;
  int r0 = lin >> 3;
  int y = r0 & 15;                          // 32-row m tile
  int t = r0 >> 4;
  int tid = threadIdx.x;
  int wave = tid >> 6, lane = tid & 63;
  int col  = lane & 15, kb = lane >> 4;
  int nt = x * 4 + wave;
  int m0 = y * 32;
  const ushort* bp = Ofrag + (size_t)nt * (64 * 3 * 512);
  const uint8_t* st = spk + (size_t)t * (512*256);

  f32x4 acc[2] = {{0.f,0.f,0.f,0.f},{0.f,0.f,0.f,0.f}};

  // prologue: aw for kc4=0, B for g=0
  u32x4 aw[2], awn[2];
#pragma unroll
  for (int f = 0; f < 2; ++f)
    aw[f] = *(const u32x4*)&st[(size_t)(m0 + f*16 + col) * 256];
  short8v Bc0, Bc1, Bc2;
  {
    const ushort* bk = bp + lane * 8;
    Bc0 = *(const short8v*)&bk[0];
    Bc1 = *(const short8v*)&bk[512];
    Bc2 = *(const short8v*)&bk[1024];
  }

  for (int kc4 = 0; kc4 < 16; ++kc4) {      // K = 2048 = 16 * 4 * 32
    int nk4 = (kc4 + 1 < 16) ? kc4 + 1 : 15;
#pragma unroll
    for (int f = 0; f < 2; ++f)
      awn[f] = *(const u32x4*)&st[(size_t)(m0 + f*16 + col) * 256 + nk4*16];
#pragma unroll
    for (int sv = 0; sv < 4; ++sv) {
      int g1 = kc4 * 4 + sv + 1;
      if (g1 > 63) g1 = 63;
      const ushort* bn = bp + (size_t)g1 * 1536 + lane * 8;
      short8v Bn0 = *(const short8v*)&bn[0];
      short8v Bn1 = *(const short8v*)&bn[512];
      short8v Bn2 = *(const short8v*)&bn[1024];
      short8v A[2];
#pragma unroll
      for (int f = 0; f < 2; ++f)
        A[f] = expand8((aw[f][sv] >> (kb*8)) & 0xFFu);
      __builtin_amdgcn_s_setprio(1);
#pragma unroll
      for (int f = 0; f < 2; ++f) acc[f] = MFMA(A[f], Bc0, acc[f]);
#pragma unroll
      for (int f = 0; f < 2; ++f) acc[f] = MFMA(A[f], Bc1, acc[f]);
#pragma unroll
      for (int f = 0; f < 2; ++f) acc[f] = MFMA(A[f], Bc2, acc[f]);
      __builtin_amdgcn_s_setprio(0);
      Bc0 = Bn0; Bc1 = Bn1; Bc2 = Bn2;
    }
#pragma unroll
    for (int f = 0; f < 2; ++f) aw[f] = awn[f];
  }
  float bo = bout[nt*16 + col];
#pragma unroll
  for (int f = 0; f < 2; ++f) {
#pragma unroll
    for (int r = 0; r < 4; ++r) {
      float out = acc[f][r] + bo;
      if (out > 0.0f) {
        int b = m0 + f*16 + kb*4 + r;
        atomicAdd(&s[(size_t)b * OUT_SZ + nt*16 + col], 1.0f);
      }
    }
  }
}

// ---------------------------------------------------------------------------
extern "C" void kernel_launch(void* const* d_in, const int* in_sizes, int n_in,
                              void* d_out, int out_size, void* d_ws, size_t ws_size,
                              hipStream_t stream) {
  const float* x    = (const float*)d_in[0];
  const float* Win  = (const float*)d_in[1];   // [2048][3072]
  const float* Wout = (const float*)d_in[2];   // [512][2048]
  const float* bout = (const float*)d_in[3];
  float* s = (float*)d_out;                    // [512][512]

  char* ws = (char*)d_ws;
  ushort*   Wfrag   = (ushort*)(ws + 0);           // 64*192*3*512*2 = 37748736
  ushort*   Ofrag   = (ushort*)(ws + 37748736);    // 32*64*3*512*2  = 6291456
  uint32_t* in_bits = (uint32_t*)(ws + 44040192);  // 10*512*96*4    = 1966080
  uint8_t*  spk     = (uint8_t*)(ws + 46006272);   // 10*512*256     = 1310720
  float*    H       = (float*)(ws + 47316992);     // 5120*2048*4    = 41943040

  Keys hk;
  for (int t = 0; t < T_STEPS; ++t) {
    uint32_t y0, y1;
    threefry2x32(0u, 42u, 0u, (uint32_t)t, y0, y1);
    hk.k[2*t] = y0; hk.k[2*t+1] = y1;
  }

  (void)hipMemsetAsync(d_out, 0, (size_t)OUT_SZ * B_SZ * sizeof(float), stream);
  hipLaunchKernelGGL(prep_kernel, dim3(3072 + 512 + NELEM/256), dim3(256), 0,
                     stream, x, Win, Wout, Wfrag, Ofrag, in_bits, hk);
  hipLaunchKernelGGL(gemm_hidden, dim3(512), dim3(256), 0, stream,
                     Wfrag, in_bits, H);
  hipLaunchKernelGGL(lif_scan, dim3((B_SZ*HID)/256), dim3(256), 0, stream,
                     H, spk);
  hipLaunchKernelGGL(out_mfma, dim3(8 * 16 * T_STEPS), dim3(256), 0, stream,
                     Ofrag, spk, bout, s);
}

// Round 17
// 214.742 us; speedup vs baseline: 1.2153x; 1.2153x over previous
//
#include <hip/hip_runtime.h>
#include <cstdint>

#define B_SZ   512
#define IN_SZ  3072
#define HID    2048
#define OUT_SZ 512
#define T_STEPS 10
#define NELEM  (512u*3072u)
#define KW     96                    // in_bits words per row
#define BITS_T_STRIDE (512u*96u)
#define M_ALL  (T_STEPS * B_SZ)
#define SCALE_UP   16384.0f          // 2^14 (exact)
#define SCALE_DN   6.103515625e-05f  // 2^-14 (exact)

typedef __attribute__((ext_vector_type(8))) _Float16 half8;   // 8 f16
typedef __attribute__((ext_vector_type(4))) float f32x4;
typedef __attribute__((ext_vector_type(16))) float f32x16;
typedef __attribute__((ext_vector_type(4))) unsigned int u32x4;

struct Keys { uint32_t k[2*T_STEPS]; };

__host__ __device__ inline void threefry2x32(uint32_t k0, uint32_t k1,
                                             uint32_t x0, uint32_t x1,
                                             uint32_t& y0, uint32_t& y1) {
  const uint32_t ks2 = k0 ^ k1 ^ 0x1BD11BDAu;
#define TF_R(r) { x0 += x1; x1 = (x1 << (r)) | (x1 >> (32-(r))); x1 ^= x0; }
  x0 += k0; x1 += k1;
  TF_R(13) TF_R(15) TF_R(26) TF_R(6)   x0 += k1;  x1 += ks2 + 1u;
  TF_R(17) TF_R(29) TF_R(16) TF_R(24)  x0 += ks2; x1 += k0  + 2u;
  TF_R(13) TF_R(15) TF_R(26) TF_R(6)   x0 += k0;  x1 += k1  + 3u;
  TF_R(17) TF_R(29) TF_R(16) TF_R(24)  x0 += k1;  x1 += ks2 + 4u;
  TF_R(13) TF_R(15) TF_R(26) TF_R(6)   x0 += ks2; x1 += k0  + 5u;
#undef TF_R
  y0 = x0; y1 = x1;
}

// ---------------- 2-way f16 split (pre-scaled by 2^14) ---------------------
// w*2^14 = hi + mid + r2, |r2| <= 2^-24 * |w*2^14|; r2 dropped.
__device__ __forceinline__ void split2x8h(const float* __restrict__ src,
                                          half8& hv, half8& mv) {
  float w8[8];
  *(f32x4*)&w8[0] = *(const f32x4*)&src[0];
  *(f32x4*)&w8[4] = *(const f32x4*)&src[4];
  union { _Float16 f[8]; half8 v; } h8, m8;
#pragma unroll
  for (int j = 0; j < 8; ++j) {
    float ws = w8[j] * SCALE_UP;           // exact (power of 2)
    _Float16 h = (_Float16)ws;             // RNE via v_cvt_f16_f32
    float r1 = ws - (float)h;              // exact
    _Float16 m = (_Float16)r1;             // RNE
    h8.f[j] = h; m8.f[j] = m;
  }
  hv = h8.v; mv = m8.v;
}

// ---------------- bit byte -> 8 f16 {0,1} ----------------------------------
__device__ __forceinline__ half8 expand8h(uint32_t b) {
  union { uint32_t u[4]; half8 v; } r;
#pragma unroll
  for (int j = 0; j < 4; ++j) {
    uint32_t x = b >> (2*j);
    r.u[j] = ((x & 1u) | ((x & 2u) << 15)) * 0x3C00u;  // f16 1.0 per set bit
  }
  return r.v;
}

// ---------------- fused prep: split32(Win) + split16(Wout) + spikegen ------
// blocks [0,3072): Win split; [3072,3584): Wout split; [3584,9728): spikegen
__global__ __launch_bounds__(256) void prep_kernel(
    const float* __restrict__ x, const float* __restrict__ Win,
    const float* __restrict__ Wout,
    ushort* __restrict__ Wfrag, ushort* __restrict__ Ofrag,
    uint32_t* __restrict__ pre_bits, Keys keys) {
  int blk = blockIdx.x;
  int tid = threadIdx.x;
  if (blk < 3072) {
    // 32-col fragment layout: out[nt32][ks16][2][512],
    // entry (kh*32+c)*8+e = W[nt*32+c][ks*16+kh*8+e]  (index math r8-16)
    int bx = blk % 48, nt = blk / 48;
    int col = tid & 31;
    int cell = tid >> 5;
    int ks = bx * 4 + (cell >> 1);
    int kh = cell & 1;
    half8 hv, mv;
    split2x8h(&Win[(size_t)(nt * 32 + col) * IN_SZ + ks * 16 + kh * 8],
              hv, mv);
    size_t base =
        ((size_t)nt * (IN_SZ / 16) + ks) * 1024 + (kh * 32 + col) * 8;
    *(half8*)&Wfrag[base]       = hv;
    *(half8*)&Wfrag[base + 512] = mv;
  } else if (blk < 3584) {
    // 16-col fragment layout: out[nt16][ks32][2][512]  (index math r5-16)
    int q = blk - 3072;
    int bx = q % 16, nt = q / 16;
    int ks = bx * 4 + (tid >> 6);
    int kb = (tid >> 4) & 3, c = tid & 15;
    half8 hv, mv;
    split2x8h(&Wout[(size_t)(nt * 16 + c) * HID + ks * 32 + kb * 8], hv, mv);
    size_t base =
        ((size_t)nt * (HID / 32) + ks) * 1024 + (kb * 16 + c) * 8;
    *(half8*)&Ofrag[base]       = hv;
    *(half8*)&Ofrag[base + 512] = mv;
  } else {
    // spike generation (verified rounds 1/3-16)
    uint32_t m = (uint32_t)(blk - 3584) * 256u + tid;
    uint32_t b = m / IN_SZ;
    uint32_t j = m - b * IN_SZ;
    float xv = x[m];
    float p = (float)(1.0 / (1.0 + exp(-(double)xv)));
    uint32_t lane = tid & 63u;
    uint32_t wbase = b * KW + (j >> 5);
#pragma unroll
    for (int t = 0; t < T_STEPS; ++t) {
      uint32_t y0, y1;
      threefry2x32(keys.k[2*t], keys.k[2*t+1], 0u, m, y0, y1);
      uint32_t bits = y0 ^ y1;
      float u = __uint_as_float((bits >> 9) | 0x3f800000u) - 1.0f;
      unsigned long long mask = __ballot(u < p);
      if (lane == 0u) {
        *reinterpret_cast<unsigned long long*>(
            &pre_bits[(uint32_t)t * BITS_T_STRIDE + wbase]) = mask;
      }
    }
  }
}

#define MFMAH(a, b, c)   __builtin_amdgcn_mfma_f32_16x16x32_f16((a), (b), (c), 0, 0, 0)
#define MFMAH32(a, b, c) __builtin_amdgcn_mfma_f32_32x32x16_f16((a), (b), (c), 0, 0, 0)

// ---------------- hidden GEMM: R15 structure, 2xf16 splits -----------------
// 256 thr (4 waves 1m x 4n), tile 160m x 128n; wave = 160m x 32n (F=5).
// grid 512 = 8 XCD x 2 xb x 32 mb -> 2 blocks/CU; LDS 40 KB; panel-ordered.
// Staged-A LDS dbuf + 2-deep B pipeline. Epilogue unscales by 2^-14 (exact).
__global__ __launch_bounds__(256) void gemm_hidden(
    const ushort* __restrict__ Wfrag,       // [64 nt][192 ks][2][512]
    const uint32_t* __restrict__ in_bits,   // [5120][96]
    float* __restrict__ H) {                // [5120][2048]
  __shared__ ushort A_lds[2][10240];        // [8 j][5 f][32 row][8 e] x2 = 40KB
  int lin = blockIdx.x;
  int xcd = lin & 7, w = lin >> 3;          // w 0..63
  int xb  = xcd * 2 + (w >> 5);             // n-panel: all mb of panel0 first
  int mb  = w & 31;                         // m-block (160 rows), 0..31
  int tid  = threadIdx.x;
  int wave = tid >> 6, lane = tid & 63;
  int col  = lane & 31, kh = lane >> 5;
  int nt = xb * 4 + wave;                   // 32-col group
  int m0 = mb * 160;
  const ushort* bp = Wfrag + (size_t)nt * (192 * 1024);

  // staging: byte-slot s = r*8 + j; thread owns slots 5t..5t+4 (r11-16)
  int s0 = tid * 5;
  int r0 = s0 >> 3, r1 = (s0 + 4) >> 3;
  const uint32_t* rowp0 = in_bits + (size_t)(m0 + r0) * KW;
  const uint32_t* rowp1 = in_bits + (size_t)(m0 + r1) * KW;
  int hi_[5], ws_[5], sh_[5], off_[5];
#pragma unroll
  for (int p = 0; p < 5; ++p) {
    int s = s0 + p, r = s >> 3, j = s & 7;
    hi_[p]  = (r != r0);
    ws_[p]  = (j >> 2) & 1;
    sh_[p]  = (j & 3) * 8;
    off_[p] = (j * 5 + (r >> 5)) * 256 + (r & 31) * 8;
  }

  f32x16 acc[5];
#pragma unroll
  for (int f = 0; f < 5; ++f)
#pragma unroll
    for (int r = 0; r < 16; ++r) acc[f][r] = 0.f;

  uint2 br0, br1;   // bits words (2 per row) for the chunk being staged

#define STAGE(buf)                                                            \
  {                                                                           \
    _Pragma("unroll")                                                         \
    for (int p = 0; p < 5; ++p) {                                             \
      uint32_t wv = hi_[p] ? (ws_[p] ? br1.y : br1.x)                         \
                           : (ws_[p] ? br0.y : br0.x);                        \
      *(half8*)&A_lds[buf][off_[p]] = expand8h((wv >> sh_[p]) & 0xFFu);       \
    }                                                                         \
  }

#define BURST(sidx)                                                           \
  {                                                                           \
    int g2 = kc * 4 + (sidx) + 2;                                             \
    if (g2 > 191) g2 = 191;                                                   \
    const ushort* bn = bp + (size_t)g2 * 1024 + lane * 8;                     \
    half8 Bn0 = *(const half8*)&bn[0];                                        \
    half8 Bn1 = *(const half8*)&bn[512];                                      \
    half8 A[5];                                                               \
    _Pragma("unroll")                                                         \
    for (int f = 0; f < 5; ++f)                                               \
      A[f] = *(const half8*)&A_lds[cur][(sidx) * 2560 + aoff + f * 256];      \
    __builtin_amdgcn_s_setprio(1);                                            \
    _Pragma("unroll")                                                         \
    for (int f = 0; f < 5; ++f) acc[f] = MFMAH32(A[f], Bc0, acc[f]);          \
    _Pragma("unroll")                                                         \
    for (int f = 0; f < 5; ++f) acc[f] = MFMAH32(A[f], Bc1, acc[f]);          \
    __builtin_amdgcn_s_setprio(0);                                            \
    Bc0 = Bd0; Bc1 = Bd1;                                                     \
    Bd0 = Bn0; Bd1 = Bn1;                                                     \
  }

  // prologue: stage chunk 0, prefetch bits chunk 1, preload B[g=0], B[g=1]
  br0 = *(const uint2*)&rowp0[0];
  br1 = *(const uint2*)&rowp1[0];
  STAGE(0)
  br0 = *(const uint2*)&rowp0[2];
  br1 = *(const uint2*)&rowp1[2];
  half8 Bc0, Bc1, Bd0, Bd1;
  {
    const ushort* bk = bp + lane * 8;
    Bc0 = *(const half8*)&bk[0];
    Bc1 = *(const half8*)&bk[512];
    const ushort* bd = bk + 1024;
    Bd0 = *(const half8*)&bd[0];
    Bd1 = *(const half8*)&bd[512];
  }
  __syncthreads();

  int aoff = kh * 5 * 256 + col * 8;   // wave's A-frag base within a j-pair

  for (int kc = 0; kc < 48; ++kc) {
    int cur = kc & 1;
    BURST(0)
    if (kc + 1 < 48) STAGE(cur ^ 1)                  // under s=0's shadow
    if (kc + 2 < 48) {                               // prefetch chunk kc+2
      br0 = *(const uint2*)&rowp0[(kc + 2) * 2];
      br1 = *(const uint2*)&rowp1[(kc + 2) * 2];
    }
    BURST(1)
    BURST(2)
    BURST(3)
    __syncthreads();
  }
#undef BURST
#undef STAGE

  // C layout (verified m74/m101, rounds 8-16): col=lane&31,
  // row=(r&3)+8*(r>>2)+4*kh.  Unscale by 2^-14 (exact).
#pragma unroll
  for (int f = 0; f < 5; ++f)
#pragma unroll
    for (int r = 0; r < 16; ++r) {
      int m = m0 + f * 32 + (r & 3) + 8 * (r >> 2) + 4 * kh;
      H[(size_t)m * HID + nt * 32 + col] = acc[f][r] * SCALE_DN;
    }
}

// ---------------- LIF scan over t (the only sequential part) ---------------
__global__ __launch_bounds__(256) void lif_scan(
    const float* __restrict__ H,           // [5120][2048]
    uint8_t* __restrict__ spk) {           // [T][512][256] bit-packed along n
  int idx  = blockIdx.x * 256 + threadIdx.x;   // 0 .. 512*2048-1
  int b = idx >> 11, n = idx & 2047;
  int lane = threadIdx.x & 63;
  size_t spk_off = (size_t)b * 256 + (size_t)((n >> 3) & ~7);
  float v = 0.f;
#pragma unroll
  for (int t = 0; t < T_STEPS; ++t) {
    float h = H[(size_t)(t * B_SZ + b) * HID + n];
    bool fire;
    {
#pragma clang fp contract(off)
      float vd = v * 0.3f;
      float vn = vd + h;
      fire = (vn >= 1.0f);
      v = fire ? 0.0f : vn;
    }
    unsigned long long mask = __ballot(fire);
    if (lane == 0)
      *(unsigned long long*)&spk[(size_t)t * (512*256) + spk_off] = mask;
  }
}

// ---------------- output layer, XCD-swizzled + B/aw pipelined, 2xf16 -------
__global__ __launch_bounds__(256) void out_mfma(
    const ushort* __restrict__ Ofrag,       // [32][64][2][512]
    const uint8_t* __restrict__ spk,        // [T][512][256]
    const float* __restrict__ bout,
    float* __restrict__ s) {                // [512][512], pre-zeroed
  int lin = blockIdx.x;
  int x = lin & 7;
  int r0 = lin >> 3;
  int y = r0 & 7;
  int t = r0 >> 3;
  int tid = threadIdx.x;
  int wave = tid >> 6, lane = tid & 63;
  int col  = lane & 15, kb = lane >> 4;
  int nt = x * 4 + wave;
  int m0 = y * 64;
  const ushort* bp = Ofrag + (size_t)nt * (64 * 1024);
  const uint8_t* st = spk + (size_t)t * (512*256);

  f32x4 acc[4] = {{0.f,0.f,0.f,0.f},{0.f,0.f,0.f,0.f},
                  {0.f,0.f,0.f,0.f},{0.f,0.f,0.f,0.f}};

  // prologue: aw for kc4=0, B for g=0
  u32x4 aw[4], awn[4];
#pragma unroll
  for (int f = 0; f < 4; ++f)
    aw[f] = *(const u32x4*)&st[(size_t)(m0 + f*16 + col) * 256];
  half8 Bc0, Bc1;
  {
    const ushort* bk = bp + lane * 8;
    Bc0 = *(const half8*)&bk[0];
    Bc1 = *(const half8*)&bk[512];
  }

  for (int kc4 = 0; kc4 < 16; ++kc4) {      // K = 2048 = 16 * 4 * 32
    int nk4 = (kc4 + 1 < 16) ? kc4 + 1 : 15;
#pragma unroll
    for (int f = 0; f < 4; ++f)
      awn[f] = *(const u32x4*)&st[(size_t)(m0 + f*16 + col) * 256 + nk4*16];
#pragma unroll
    for (int sv = 0; sv < 4; ++sv) {
      int g1 = kc4 * 4 + sv + 1;
      if (g1 > 63) g1 = 63;
      const ushort* bn = bp + (size_t)g1 * 1024 + lane * 8;
      half8 Bn0 = *(const half8*)&bn[0];
      half8 Bn1 = *(const half8*)&bn[512];
      half8 A[4];
#pragma unroll
      for (int f = 0; f < 4; ++f)
        A[f] = expand8h((aw[f][sv] >> (kb*8)) & 0xFFu);
      __builtin_amdgcn_s_setprio(1);
#pragma unroll
      for (int f = 0; f < 4; ++f) acc[f] = MFMAH(A[f], Bc0, acc[f]);
#pragma unroll
      for (int f = 0; f < 4; ++f) acc[f] = MFMAH(A[f], Bc1, acc[f]);
      __builtin_amdgcn_s_setprio(0);
      Bc0 = Bn0; Bc1 = Bn1;
    }
#pragma unroll
    for (int f = 0; f < 4; ++f) aw[f] = awn[f];
  }
  float bo = bout[nt*16 + col];
#pragma unroll
  for (int f = 0; f < 4; ++f) {
#pragma unroll
    for (int r = 0; r < 4; ++r) {
      // acc*2^-14 exact; single rounding on +bo (same as unscaled path)
      float out = acc[f][r] * SCALE_DN + bo;
      if (out > 0.0f) {
        int b = m0 + f*16 + kb*4 + r;
        atomicAdd(&s[(size_t)b * OUT_SZ + nt*16 + col], 1.0f);
      }
    }
  }
}

// ---------------------------------------------------------------------------
extern "C" void kernel_launch(void* const* d_in, const int* in_sizes, int n_in,
                              void* d_out, int out_size, void* d_ws, size_t ws_size,
                              hipStream_t stream) {
  const float* x    = (const float*)d_in[0];
  const float* Win  = (const float*)d_in[1];   // [2048][3072]
  const float* Wout = (const float*)d_in[2];   // [512][2048]
  const float* bout = (const float*)d_in[3];
  float* s = (float*)d_out;                    // [512][512]

  char* ws = (char*)d_ws;
  ushort*   Wfrag   = (ushort*)(ws + 0);           // 64*192*1024*2 = 25165824
  ushort*   Ofrag   = (ushort*)(ws + 25165824);    // 32*64*1024*2  = 4194304
  uint32_t* in_bits = (uint32_t*)(ws + 29360128);  // 10*512*96*4   = 1966080
  uint8_t*  spk     = (uint8_t*)(ws + 31326208);   // 10*512*256    = 1310720
  float*    H       = (float*)(ws + 32636928);     // 5120*2048*4   = 41943040

  Keys hk;
  for (int t = 0; t < T_STEPS; ++t) {
    uint32_t y0, y1;
    threefry2x32(0u, 42u, 0u, (uint32_t)t, y0, y1);
    hk.k[2*t] = y0; hk.k[2*t+1] = y1;
  }

  (void)hipMemsetAsync(d_out, 0, (size_t)OUT_SZ * B_SZ * sizeof(float), stream);
  hipLaunchKernelGGL(prep_kernel, dim3(3072 + 512 + NELEM/256), dim3(256), 0,
                     stream, x, Win, Wout, Wfrag, Ofrag, in_bits, hk);
  hipLaunchKernelGGL(gemm_hidden, dim3(512), dim3(256), 0, stream,
                     Wfrag, in_bits, H);
  hipLaunchKernelGGL(lif_scan, dim3((B_SZ*HID)/256), dim3(256), 0, stream,
                     H, spk);
  hipLaunchKernelGGL(out_mfma, dim3(8 * 8 * T_STEPS), dim3(256), 0, stream,
                     Ofrag, spk, bout, s);
}